// Round 1
// baseline (6857.971 us; speedup 1.0000x reference)
//
#include <hip/hip_runtime.h>
#include <hip/hip_bf16.h>

#define NN 50000
#define NE 800000

// ---------------------------------------------------------------------------
// Kernel 1: qkv[n, o] = feat[n,:] . qkv_w[o,:] + qkv_b[o]      (N x 384)
// Block: 384 threads (one per output column), 32 nodes per block.
// feat tile in LDS (broadcast reads), W rows streamed global->regs (L2-hot).
// ---------------------------------------------------------------------------
__global__ __launch_bounds__(384) void qkv_gemm(
    const float* __restrict__ feat, const float* __restrict__ w,
    const float* __restrict__ bias, float* __restrict__ qkv)
{
    __shared__ float As[32 * 128];           // 16 KB, row-major [m][k]
    const int t = threadIdx.x;
    const int bm = blockIdx.x * 32;

    const float4* fv = (const float4*)feat;
    float4* Asv = (float4*)As;
    for (int idx = t; idx < 32 * 32; idx += 384) {
        int row = idx >> 5, c4 = idx & 31;
        int g = bm + row;
        float4 val = (g < NN) ? fv[(size_t)g * 32 + c4] : make_float4(0.f, 0.f, 0.f, 0.f);
        Asv[idx] = val;
    }
    __syncthreads();

    const int n = t;                          // 0..383
    float acc[32];
#pragma unroll
    for (int m = 0; m < 32; ++m) acc[m] = 0.f;

    const float4* wv = (const float4*)(w + (size_t)n * 128);
#pragma unroll
    for (int kb = 0; kb < 8; ++kb) {
        float4 w0 = wv[kb * 4 + 0];
        float4 w1 = wv[kb * 4 + 1];
        float4 w2 = wv[kb * 4 + 2];
        float4 w3 = wv[kb * 4 + 3];
#pragma unroll
        for (int m = 0; m < 32; ++m) {
            const float4* a = &Asv[m * 32 + kb * 4];
            float4 a0 = a[0], a1 = a[1], a2 = a[2], a3 = a[3];
            acc[m] += a0.x * w0.x + a0.y * w0.y + a0.z * w0.z + a0.w * w0.w
                    + a1.x * w1.x + a1.y * w1.y + a1.z * w1.z + a1.w * w1.w
                    + a2.x * w2.x + a2.y * w2.y + a2.z * w2.z + a2.w * w2.w
                    + a3.x * w3.x + a3.y * w3.y + a3.z * w3.z + a3.w * w3.w;
        }
    }

    const float b = bias[n];
#pragma unroll
    for (int m = 0; m < 32; ++m) {
        int g = bm + m;
        if (g < NN) qkv[(size_t)g * 384 + n] = acc[m] + b;
    }
}

// ---------------------------------------------------------------------------
// Kernel 2: per-edge attention logits + exp + atomic scatter of ex*v and ex.
// 32 lanes per edge (lane j handles channels 4j..4j+3, head h = j>>3).
// rpe term collapsed: sum_d rpe[h,d] = rel . rw_sum[h] + rb_sum[h].
// ---------------------------------------------------------------------------
__global__ __launch_bounds__(256) void edge_attn(
    const float* __restrict__ qkv, const float* __restrict__ coord,
    const int* __restrict__ graph, const float* __restrict__ rpe_w,
    const float* __restrict__ rpe_b, float* __restrict__ outa,
    float* __restrict__ denom)
{
    __shared__ float s_rw[12];   // [h][p]
    __shared__ float s_rb[4];
    const int t = threadIdx.x;
    if (t < 12) {
        int h = t / 3, p = t % 3;
        float s = 0.f;
        for (int d = 0; d < 32; ++d) s += rpe_w[(h * 32 + d) * 3 + p];
        s_rw[t] = s;
    } else if (t < 16) {
        int h = t - 12;
        float s = 0.f;
        for (int d = 0; d < 32; ++d) s += rpe_b[h * 32 + d];
        s_rb[h] = s;
    }
    __syncthreads();

    const int e = blockIdx.x * 8 + (t >> 5);
    if (e >= NE) return;
    const int j = t & 31;
    const int h = j >> 3;

    const int dst = graph[e];
    const int src = graph[NE + e];

    const float r0 = coord[dst * 3 + 0] - coord[src * 3 + 0];
    const float r1 = coord[dst * 3 + 1] - coord[src * 3 + 1];
    const float r2 = coord[dst * 3 + 2] - coord[src * 3 + 2];

    const float4* qp = (const float4*)(qkv + (size_t)dst * 384);
    const float4* kp = (const float4*)(qkv + (size_t)src * 384);

    float4 q4 = qp[j];            // q: cols 0..127
    float4 k4 = kp[32 + j];       // k: cols 128..255
    float part = q4.x * k4.x + q4.y * k4.y + q4.z * k4.z + q4.w * k4.w;
    // 8-lane (per-head) butterfly reduce; every lane ends with the head sum
    part += __shfl_xor(part, 1);
    part += __shfl_xor(part, 2);
    part += __shfl_xor(part, 4);

    float logit = part + r0 * s_rw[h * 3 + 0] + r1 * s_rw[h * 3 + 1]
                       + r2 * s_rw[h * 3 + 2] + s_rb[h];
    float ex = expf(logit);       // no max-subtraction needed (|logit| << 88)

    if ((j & 7) == 0) unsafeAtomicAdd(&denom[dst * 4 + h], ex);

    float4 v4 = kp[64 + j];       // v: cols 256..383 (same base as k pointer)
    // note: kp base is src row, v4 = qkv[src*384 + 256 + 4j .. +3]
    float* op = outa + (size_t)dst * 128 + j * 4;
    unsafeAtomicAdd(op + 0, ex * v4.x);
    unsafeAtomicAdd(op + 1, ex * v4.y);
    unsafeAtomicAdd(op + 2, ex * v4.z);
    unsafeAtomicAdd(op + 3, ex * v4.w);
}

// ---------------------------------------------------------------------------
// Kernel 3: out[n, h*32+d] /= denom[n,h]   (0 if empty segment)
// ---------------------------------------------------------------------------
__global__ __launch_bounds__(256) void normalize_out(
    float* __restrict__ out, const float* __restrict__ denom)
{
    int idx = blockIdx.x * 256 + threadIdx.x;   // one float4 per thread
    if (idx >= NN * 32) return;
    int n = idx >> 5;
    int h = (idx >> 3) & 3;
    float d = denom[n * 4 + h];
    float inv = (d > 0.f) ? 1.0f / d : 0.f;
    float4* o = (float4*)out;
    float4 v = o[idx];
    v.x *= inv; v.y *= inv; v.z *= inv; v.w *= inv;
    o[idx] = v;
}

extern "C" void kernel_launch(void* const* d_in, const int* in_sizes, int n_in,
                              void* d_out, int out_size, void* d_ws, size_t ws_size,
                              hipStream_t stream) {
    const float* feat  = (const float*)d_in[0];
    const float* coord = (const float*)d_in[1];
    const int*   graph = (const int*)d_in[2];
    const float* qkv_w = (const float*)d_in[3];
    const float* qkv_b = (const float*)d_in[4];
    const float* rpe_w = (const float*)d_in[5];
    const float* rpe_b = (const float*)d_in[6];
    float* out = (float*)d_out;

    float* qkv   = (float*)d_ws;                  // N x 384
    float* denom = qkv + (size_t)NN * 384;        // N x 4

    hipMemsetAsync(out, 0, (size_t)NN * 128 * sizeof(float), stream);
    hipMemsetAsync(denom, 0, (size_t)NN * 4 * sizeof(float), stream);

    qkv_gemm<<<dim3((NN + 31) / 32), 384, 0, stream>>>(feat, qkv_w, qkv_b, qkv);
    edge_attn<<<dim3((NE + 7) / 8), 256, 0, stream>>>(qkv, coord, graph,
                                                      rpe_w, rpe_b, out, denom);
    normalize_out<<<dim3((NN * 32 + 255) / 256), 256, 0, stream>>>(out, denom);
}

// Round 2
// 1656.075 us; speedup vs baseline: 4.1411x; 4.1411x over previous
//
#include <hip/hip_runtime.h>
#include <hip/hip_bf16.h>

#define NN 50000
#define NE 800000

// ---------------------------------------------------------------------------
// Kernel 1: qkv[n, o] = feat[n,:] . qkv_w[o,:] + qkv_b[o]      (N x 384)
// Block: 384 threads (one per output column), 16 nodes per block.
// Small live set (acc[16] + w4 + a4 ~ 32 VGPR) -> no spills. k-loop rolled.
// feat tile in LDS (wave-uniform broadcast reads); W rows stream from L2.
// ---------------------------------------------------------------------------
__global__ __launch_bounds__(384) void qkv_gemm(
    const float* __restrict__ feat, const float* __restrict__ w,
    const float* __restrict__ bias, float* __restrict__ qkv)
{
    __shared__ float As[16 * 128];           // 8 KB, row-major [m][k]
    const int t = threadIdx.x;               // output column 0..383
    const int bm = blockIdx.x * 16;

    const float4* fv = (const float4*)feat;
    float4* Asv = (float4*)As;
    for (int idx = t; idx < 16 * 32; idx += 384) {
        int row = idx >> 5, c4 = idx & 31;
        int g = bm + row;
        Asv[idx] = (g < NN) ? fv[(size_t)g * 32 + c4] : make_float4(0.f, 0.f, 0.f, 0.f);
    }
    __syncthreads();

    float acc[16];
#pragma unroll
    for (int m = 0; m < 16; ++m) acc[m] = 0.f;

    const float4* wv = (const float4*)(w + (size_t)t * 128);
    for (int kc = 0; kc < 32; ++kc) {        // rolled: keeps live set tiny
        float4 w4 = wv[kc];
#pragma unroll
        for (int m = 0; m < 16; ++m) {
            float4 a4 = Asv[m * 32 + kc];    // wave-uniform broadcast read
            acc[m] += a4.x * w4.x + a4.y * w4.y + a4.z * w4.z + a4.w * w4.w;
        }
    }

    const float b = bias[t];
#pragma unroll
    for (int m = 0; m < 16; ++m) {
        int g = bm + m;
        if (g < NN) qkv[(size_t)g * 384 + t] = acc[m] + b;
    }
}

// ---------------------------------------------------------------------------
// Kernel 2: per-edge attention logits + exp + atomic scatter of ex*v and ex.
// 32 lanes per edge (lane j handles channels 4j..4j+3, head h = j>>3).
// rpe term collapsed: sum_d rpe[h,d] = rel . rw_sum[h] + rb_sum[h].
// ---------------------------------------------------------------------------
__global__ __launch_bounds__(256) void edge_attn(
    const float* __restrict__ qkv, const float* __restrict__ coord,
    const int* __restrict__ graph, const float* __restrict__ rpe_w,
    const float* __restrict__ rpe_b, float* __restrict__ outa,
    float* __restrict__ denom)
{
    __shared__ float s_rw[12];   // [h][p]
    __shared__ float s_rb[4];
    const int t = threadIdx.x;
    if (t < 12) {
        int h = t / 3, p = t % 3;
        float s = 0.f;
        for (int d = 0; d < 32; ++d) s += rpe_w[(h * 32 + d) * 3 + p];
        s_rw[t] = s;
    } else if (t < 16) {
        int h = t - 12;
        float s = 0.f;
        for (int d = 0; d < 32; ++d) s += rpe_b[h * 32 + d];
        s_rb[h] = s;
    }
    __syncthreads();

    const int e = blockIdx.x * 8 + (t >> 5);
    if (e >= NE) return;
    const int j = t & 31;
    const int h = j >> 3;

    const int dst = graph[e];
    const int src = graph[NE + e];

    const float r0 = coord[dst * 3 + 0] - coord[src * 3 + 0];
    const float r1 = coord[dst * 3 + 1] - coord[src * 3 + 1];
    const float r2 = coord[dst * 3 + 2] - coord[src * 3 + 2];

    const float4* qp = (const float4*)(qkv + (size_t)dst * 384);
    const float4* kp = (const float4*)(qkv + (size_t)src * 384);

    float4 q4 = qp[j];            // q: cols 0..127
    float4 k4 = kp[32 + j];       // k: cols 128..255
    float part = q4.x * k4.x + q4.y * k4.y + q4.z * k4.z + q4.w * k4.w;
    // 8-lane (per-head) butterfly reduce; every lane ends with the head sum
    part += __shfl_xor(part, 1);
    part += __shfl_xor(part, 2);
    part += __shfl_xor(part, 4);

    float logit = part + r0 * s_rw[h * 3 + 0] + r1 * s_rw[h * 3 + 1]
                       + r2 * s_rw[h * 3 + 2] + s_rb[h];
    float ex = expf(logit);       // no max-subtraction needed (|logit| << 88)

    if ((j & 7) == 0) unsafeAtomicAdd(&denom[dst * 4 + h], ex);

    float4 v4 = kp[64 + j];       // v: cols 256..383 (src row)
    float* op = outa + (size_t)dst * 128 + j * 4;
    unsafeAtomicAdd(op + 0, ex * v4.x);
    unsafeAtomicAdd(op + 1, ex * v4.y);
    unsafeAtomicAdd(op + 2, ex * v4.z);
    unsafeAtomicAdd(op + 3, ex * v4.w);
}

// ---------------------------------------------------------------------------
// Kernel 3: out[n, h*32+d] /= denom[n,h]   (0 if empty segment)
// ---------------------------------------------------------------------------
__global__ __launch_bounds__(256) void normalize_out(
    float* __restrict__ out, const float* __restrict__ denom)
{
    int idx = blockIdx.x * 256 + threadIdx.x;   // one float4 per thread
    if (idx >= NN * 32) return;
    int n = idx >> 5;
    int h = (idx >> 3) & 3;
    float d = denom[n * 4 + h];
    float inv = (d > 0.f) ? 1.0f / d : 0.f;
    float4* o = (float4*)out;
    float4 v = o[idx];
    v.x *= inv; v.y *= inv; v.z *= inv; v.w *= inv;
    o[idx] = v;
}

extern "C" void kernel_launch(void* const* d_in, const int* in_sizes, int n_in,
                              void* d_out, int out_size, void* d_ws, size_t ws_size,
                              hipStream_t stream) {
    const float* feat  = (const float*)d_in[0];
    const float* coord = (const float*)d_in[1];
    const int*   graph = (const int*)d_in[2];
    const float* qkv_w = (const float*)d_in[3];
    const float* qkv_b = (const float*)d_in[4];
    const float* rpe_w = (const float*)d_in[5];
    const float* rpe_b = (const float*)d_in[6];
    float* out = (float*)d_out;

    float* qkv   = (float*)d_ws;                  // N x 384
    float* denom = qkv + (size_t)NN * 384;        // N x 4

    hipMemsetAsync(out, 0, (size_t)NN * 128 * sizeof(float), stream);
    hipMemsetAsync(denom, 0, (size_t)NN * 4 * sizeof(float), stream);

    qkv_gemm<<<dim3((NN + 15) / 16), 384, 0, stream>>>(feat, qkv_w, qkv_b, qkv);
    edge_attn<<<dim3((NE + 7) / 8), 256, 0, stream>>>(qkv, coord, graph,
                                                      rpe_w, rpe_b, out, denom);
    normalize_out<<<dim3((NN * 32 + 255) / 256), 256, 0, stream>>>(out, denom);
}

// Round 3
// 454.703 us; speedup vs baseline: 15.0823x; 3.6421x over previous
//
#include <hip/hip_runtime.h>
#include <hip/hip_bf16.h>

#define NN 50000
#define NE 800000

// ---------------------------------------------------------------------------
// Kernel 1: qkv[n, o] = feat[n,:] . qkv_w[o,:] + qkv_b[o]      (N x 384)
// (unchanged from R2 — spill-free rolled k-loop, 16 nodes/block)
// ---------------------------------------------------------------------------
__global__ __launch_bounds__(384) void qkv_gemm(
    const float* __restrict__ feat, const float* __restrict__ w,
    const float* __restrict__ bias, float* __restrict__ qkv)
{
    __shared__ float As[16 * 128];
    const int t = threadIdx.x;
    const int bm = blockIdx.x * 16;

    const float4* fv = (const float4*)feat;
    float4* Asv = (float4*)As;
    for (int idx = t; idx < 16 * 32; idx += 384) {
        int row = idx >> 5, c4 = idx & 31;
        int g = bm + row;
        Asv[idx] = (g < NN) ? fv[(size_t)g * 32 + c4] : make_float4(0.f, 0.f, 0.f, 0.f);
    }
    __syncthreads();

    float acc[16];
#pragma unroll
    for (int m = 0; m < 16; ++m) acc[m] = 0.f;

    const float4* wv = (const float4*)(w + (size_t)t * 128);
    for (int kc = 0; kc < 32; ++kc) {
        float4 w4 = wv[kc];
#pragma unroll
        for (int m = 0; m < 16; ++m) {
            float4 a4 = Asv[m * 32 + kc];
            acc[m] += a4.x * w4.x + a4.y * w4.y + a4.z * w4.z + a4.w * w4.w;
        }
    }

    const float b = bias[t];
#pragma unroll
    for (int m = 0; m < 16; ++m) {
        int g = bm + m;
        if (g < NN) qkv[(size_t)g * 384 + t] = acc[m] + b;
    }
}

// ---------------------------------------------------------------------------
// CSR build (unordered segments — segment order across nodes is irrelevant)
// ---------------------------------------------------------------------------
__global__ __launch_bounds__(256) void k_hist(
    const int* __restrict__ graph, int* __restrict__ deg)
{
    int e = blockIdx.x * 256 + threadIdx.x;
    if (e < NE) atomicAdd(&deg[graph[e]], 1);
}

// one atomic per WAVE (not per thread): wave-scan of degrees, then base via
// a single atomicAdd of the wave total. Avoids 50K serialized same-address atomics.
__global__ __launch_bounds__(256) void k_offsets(
    const int* __restrict__ deg, int* __restrict__ row_start,
    int* __restrict__ cursor, int* __restrict__ counter)
{
    int n = blockIdx.x * 256 + threadIdx.x;
    int lane = threadIdx.x & 63;
    int d = (n < NN) ? deg[n] : 0;
    int x = d;                       // inclusive wave prefix sum
#pragma unroll
    for (int off = 1; off < 64; off <<= 1) {
        int y = __shfl_up(x, off);
        if (lane >= off) x += y;
    }
    int wave_base = 0;
    if (lane == 63) wave_base = atomicAdd(counter, x);
    wave_base = __shfl(wave_base, 63);
    if (n < NN) {
        int s = wave_base + x - d;   // exclusive position for this node
        row_start[n] = s;
        cursor[n] = s;
    }
}

__global__ __launch_bounds__(256) void k_scatter(
    const int* __restrict__ graph, int* __restrict__ cursor,
    int* __restrict__ sorted_src)
{
    int e = blockIdx.x * 256 + threadIdx.x;
    if (e < NE) {
        int dst = graph[e];
        int src = graph[NE + e];
        int slot = atomicAdd(&cursor[dst], 1);
        sorted_src[slot] = src;
    }
}

// ---------------------------------------------------------------------------
// Kernel 2: per-node attention. 32 lanes per node (lane j: channels 4j..4j+3,
// head h = j>>3). Registers accumulate ex*v and ex; normalize fused; single
// coalesced write per node. Zero fp32 atomics.
// rpe collapsed: sum_d rpe[e,h,d] = rel . rw_sum[h] + rb_sum[h].
// ---------------------------------------------------------------------------
__global__ __launch_bounds__(256) void node_attn(
    const float* __restrict__ qkv, const float* __restrict__ coord,
    const int* __restrict__ row_start, const int* __restrict__ deg,
    const int* __restrict__ sorted_src, const float* __restrict__ rpe_w,
    const float* __restrict__ rpe_b, float* __restrict__ out)
{
    __shared__ float s_rw[12];
    __shared__ float s_rb[4];
    const int t = threadIdx.x;
    if (t < 12) {
        int h = t / 3, p = t % 3;
        float s = 0.f;
        for (int d = 0; d < 32; ++d) s += rpe_w[(h * 32 + d) * 3 + p];
        s_rw[t] = s;
    } else if (t < 16) {
        int h = t - 12;
        float s = 0.f;
        for (int d = 0; d < 32; ++d) s += rpe_b[h * 32 + d];
        s_rb[h] = s;
    }
    __syncthreads();

    const int n = blockIdx.x * 8 + (t >> 5);
    if (n >= NN) return;
    const int j = t & 31;
    const int h = j >> 3;

    const float4 q4 = ((const float4*)(qkv + (size_t)n * 384))[j];
    const float c0 = coord[n * 3 + 0];
    const float c1 = coord[n * 3 + 1];
    const float c2 = coord[n * 3 + 2];
    const float rw0 = s_rw[h * 3 + 0], rw1 = s_rw[h * 3 + 1],
                rw2 = s_rw[h * 3 + 2], rb = s_rb[h];

    const int start = row_start[n];
    const int d = deg[n];

    float4 acc = make_float4(0.f, 0.f, 0.f, 0.f);
    float den = 0.f;

    int src = (d > 0) ? sorted_src[start] : 0;
    for (int i = 0; i < d; ++i) {
        int src_next = (i + 1 < d) ? sorted_src[start + i + 1] : 0;  // prefetch
        const float4* kp = (const float4*)(qkv + (size_t)src * 384);
        float4 k4 = kp[32 + j];     // k row
        float4 v4 = kp[64 + j];     // v row
        float r0 = c0 - coord[src * 3 + 0];
        float r1 = c1 - coord[src * 3 + 1];
        float r2 = c2 - coord[src * 3 + 2];

        float part = q4.x * k4.x + q4.y * k4.y + q4.z * k4.z + q4.w * k4.w;
        part += __shfl_xor(part, 1);   // 8-lane per-head butterfly
        part += __shfl_xor(part, 2);
        part += __shfl_xor(part, 4);

        float ex = expf(part + r0 * rw0 + r1 * rw1 + r2 * rw2 + rb);
        den += ex;
        acc.x += ex * v4.x; acc.y += ex * v4.y;
        acc.z += ex * v4.z; acc.w += ex * v4.w;
        src = src_next;
    }

    float inv = (den > 0.f) ? 1.0f / den : 0.f;
    float4 o = make_float4(acc.x * inv, acc.y * inv, acc.z * inv, acc.w * inv);
    ((float4*)(out + (size_t)n * 128))[j] = o;
}

extern "C" void kernel_launch(void* const* d_in, const int* in_sizes, int n_in,
                              void* d_out, int out_size, void* d_ws, size_t ws_size,
                              hipStream_t stream) {
    const float* feat  = (const float*)d_in[0];
    const float* coord = (const float*)d_in[1];
    const int*   graph = (const int*)d_in[2];
    const float* qkv_w = (const float*)d_in[3];
    const float* qkv_b = (const float*)d_in[4];
    const float* rpe_w = (const float*)d_in[5];
    const float* rpe_b = (const float*)d_in[6];
    float* out = (float*)d_out;

    float* qkv        = (float*)d_ws;                  // NN x 384 fp32
    int*   deg        = (int*)(qkv + (size_t)NN * 384);
    int*   row_start  = deg + NN;
    int*   cursor     = row_start + NN;
    int*   counter    = cursor + NN;
    int*   sorted_src = counter + 1;

    hipMemsetAsync(deg, 0, NN * sizeof(int), stream);
    hipMemsetAsync(counter, 0, sizeof(int), stream);

    qkv_gemm<<<dim3((NN + 15) / 16), 384, 0, stream>>>(feat, qkv_w, qkv_b, qkv);
    k_hist   <<<dim3((NE + 255) / 256), 256, 0, stream>>>(graph, deg);
    k_offsets<<<dim3((NN + 255) / 256), 256, 0, stream>>>(deg, row_start, cursor, counter);
    k_scatter<<<dim3((NE + 255) / 256), 256, 0, stream>>>(graph, cursor, sorted_src);
    node_attn<<<dim3((NN + 7) / 8), 256, 0, stream>>>(qkv, coord, row_start, deg,
                                                      sorted_src, rpe_w, rpe_b, out);
}

// Round 4
// 375.205 us; speedup vs baseline: 18.2779x; 1.2119x over previous
//
#include <hip/hip_runtime.h>
#include <hip/hip_bf16.h>

#define NN 50000
#define NE 800000

// ---------------------------------------------------------------------------
// Kernel 1: qkv[n, o] = feat[n,:] . qkv_w[o,:] + qkv_b[o]      (N x 384)
// Register-tiled fp32 GEMM: 128x128 tile/block, 256 threads, 8x8 micro-tile
// per thread (4+4 split). A and B staged k-transposed in LDS (As[k][row],
// Bs[k][col]) so compute reads 4 x ds_read_b128 per k for 64 FMAs (16:1).
// R3 version was LDS-issue-bound at 4:1 (171 us); this is VALU-bound.
// ---------------------------------------------------------------------------
__global__ __launch_bounds__(256) void qkv_gemm(
    const float* __restrict__ feat, const float* __restrict__ w,
    const float* __restrict__ bias, float* __restrict__ qkv)
{
    __shared__ float As[16][128];   // [k][row]  8 KB
    __shared__ float Bs[16][128];   // [k][col]  8 KB
    const int t  = threadIdx.x;
    const int tx = t & 15;          // col group
    const int ty = t >> 4;          // row group (0..15)
    const int bm = blockIdx.x * 128;
    const int bc = blockIdx.y * 128;

    float acc[8][8];
#pragma unroll
    for (int i = 0; i < 8; ++i)
#pragma unroll
        for (int j = 0; j < 8; ++j) acc[i][j] = 0.f;

    const int outer = t & 127;      // staging: row (A) / col (B) within tile
    const int kq0   = t >> 7;       // 0..1 -> this thread stages chunks kq0, kq0+2

    for (int k0 = 0; k0 < 128; k0 += 16) {
#pragma unroll
        for (int r = 0; r < 2; ++r) {
            int q = kq0 + r * 2;    // which float4 (4 k's) of the 16-k slab
            int ga = bm + outer;
            float4 a4 = (ga < NN)
                ? *(const float4*)(feat + (size_t)ga * 128 + k0 + q * 4)
                : make_float4(0.f, 0.f, 0.f, 0.f);
            As[q * 4 + 0][outer] = a4.x; As[q * 4 + 1][outer] = a4.y;
            As[q * 4 + 2][outer] = a4.z; As[q * 4 + 3][outer] = a4.w;
            int gb = bc + outer;    // always < 384
            float4 b4 = *(const float4*)(w + (size_t)gb * 128 + k0 + q * 4);
            Bs[q * 4 + 0][outer] = b4.x; Bs[q * 4 + 1][outer] = b4.y;
            Bs[q * 4 + 2][outer] = b4.z; Bs[q * 4 + 3][outer] = b4.w;
        }
        __syncthreads();
#pragma unroll
        for (int k = 0; k < 16; ++k) {
            float4 a0 = *(const float4*)&As[k][ty * 4];
            float4 a1 = *(const float4*)&As[k][64 + ty * 4];
            float4 b0 = *(const float4*)&Bs[k][tx * 4];
            float4 b1 = *(const float4*)&Bs[k][64 + tx * 4];
            float ar[8] = {a0.x, a0.y, a0.z, a0.w, a1.x, a1.y, a1.z, a1.w};
            float br[8] = {b0.x, b0.y, b0.z, b0.w, b1.x, b1.y, b1.z, b1.w};
#pragma unroll
            for (int i = 0; i < 8; ++i)
#pragma unroll
                for (int j = 0; j < 8; ++j)
                    acc[i][j] += ar[i] * br[j];
        }
        __syncthreads();
    }

    float bj[8];
#pragma unroll
    for (int j = 0; j < 8; ++j) {
        int col = bc + ((j < 4) ? (tx * 4 + j) : (64 + tx * 4 + (j - 4)));
        bj[j] = bias[col];
    }
#pragma unroll
    for (int i = 0; i < 8; ++i) {
        int row = bm + ((i < 4) ? (ty * 4 + i) : (64 + ty * 4 + (i - 4)));
        if (row < NN) {
            float4 o0 = make_float4(acc[i][0] + bj[0], acc[i][1] + bj[1],
                                    acc[i][2] + bj[2], acc[i][3] + bj[3]);
            float4 o1 = make_float4(acc[i][4] + bj[4], acc[i][5] + bj[5],
                                    acc[i][6] + bj[6], acc[i][7] + bj[7]);
            *(float4*)(qkv + (size_t)row * 384 + bc + tx * 4) = o0;
            *(float4*)(qkv + (size_t)row * 384 + bc + 64 + tx * 4) = o1;
        }
    }
}

// ---------------------------------------------------------------------------
// CSR build (unordered segments — segment order across nodes is irrelevant)
// ---------------------------------------------------------------------------
__global__ __launch_bounds__(256) void k_hist(
    const int* __restrict__ graph, int* __restrict__ deg)
{
    int e = blockIdx.x * 256 + threadIdx.x;
    if (e < NE) atomicAdd(&deg[graph[e]], 1);
}

__global__ __launch_bounds__(256) void k_offsets(
    const int* __restrict__ deg, int* __restrict__ row_start,
    int* __restrict__ cursor, int* __restrict__ counter)
{
    int n = blockIdx.x * 256 + threadIdx.x;
    int lane = threadIdx.x & 63;
    int d = (n < NN) ? deg[n] : 0;
    int x = d;                       // inclusive wave prefix sum
#pragma unroll
    for (int off = 1; off < 64; off <<= 1) {
        int y = __shfl_up(x, off);
        if (lane >= off) x += y;
    }
    int wave_base = 0;
    if (lane == 63) wave_base = atomicAdd(counter, x);
    wave_base = __shfl(wave_base, 63);
    if (n < NN) {
        int s = wave_base + x - d;
        row_start[n] = s;
        cursor[n] = s;
    }
}

__global__ __launch_bounds__(256) void k_scatter(
    const int* __restrict__ graph, int* __restrict__ cursor,
    int* __restrict__ sorted_src)
{
    int e = blockIdx.x * 256 + threadIdx.x;
    if (e < NE) {
        int dst = graph[e];
        int src = graph[NE + e];
        int slot = atomicAdd(&cursor[dst], 1);
        sorted_src[slot] = src;
    }
}

// ---------------------------------------------------------------------------
// Kernel 2: per-node attention. 32 lanes per node (lane j: channels 4j..4j+3,
// head h = j>>3). Registers accumulate ex*v and ex; normalize fused; single
// coalesced write per node. Zero fp32 atomics.
// rpe collapsed: sum_d rpe[e,h,d] = rel . rw_sum[h] + rb_sum[h].
// ---------------------------------------------------------------------------
__global__ __launch_bounds__(256) void node_attn(
    const float* __restrict__ qkv, const float* __restrict__ coord,
    const int* __restrict__ row_start, const int* __restrict__ deg,
    const int* __restrict__ sorted_src, const float* __restrict__ rpe_w,
    const float* __restrict__ rpe_b, float* __restrict__ out)
{
    __shared__ float s_rw[12];
    __shared__ float s_rb[4];
    const int t = threadIdx.x;
    if (t < 12) {
        int h = t / 3, p = t % 3;
        float s = 0.f;
        for (int d = 0; d < 32; ++d) s += rpe_w[(h * 32 + d) * 3 + p];
        s_rw[t] = s;
    } else if (t < 16) {
        int h = t - 12;
        float s = 0.f;
        for (int d = 0; d < 32; ++d) s += rpe_b[h * 32 + d];
        s_rb[h] = s;
    }
    __syncthreads();

    const int n = blockIdx.x * 8 + (t >> 5);
    if (n >= NN) return;
    const int j = t & 31;
    const int h = j >> 3;

    const float4 q4 = ((const float4*)(qkv + (size_t)n * 384))[j];
    const float c0 = coord[n * 3 + 0];
    const float c1 = coord[n * 3 + 1];
    const float c2 = coord[n * 3 + 2];
    const float rw0 = s_rw[h * 3 + 0], rw1 = s_rw[h * 3 + 1],
                rw2 = s_rw[h * 3 + 2], rb = s_rb[h];

    const int start = row_start[n];
    const int d = deg[n];

    float4 acc = make_float4(0.f, 0.f, 0.f, 0.f);
    float den = 0.f;

    int src = (d > 0) ? sorted_src[start] : 0;
    for (int i = 0; i < d; ++i) {
        int src_next = (i + 1 < d) ? sorted_src[start + i + 1] : 0;  // prefetch
        const float4* kp = (const float4*)(qkv + (size_t)src * 384);
        float4 k4 = kp[32 + j];     // k row
        float4 v4 = kp[64 + j];     // v row
        float r0 = c0 - coord[src * 3 + 0];
        float r1 = c1 - coord[src * 3 + 1];
        float r2 = c2 - coord[src * 3 + 2];

        float part = q4.x * k4.x + q4.y * k4.y + q4.z * k4.z + q4.w * k4.w;
        part += __shfl_xor(part, 1);   // 8-lane per-head butterfly
        part += __shfl_xor(part, 2);
        part += __shfl_xor(part, 4);

        float ex = expf(part + r0 * rw0 + r1 * rw1 + r2 * rw2 + rb);
        den += ex;
        acc.x += ex * v4.x; acc.y += ex * v4.y;
        acc.z += ex * v4.z; acc.w += ex * v4.w;
        src = src_next;
    }

    float inv = (den > 0.f) ? 1.0f / den : 0.f;
    float4 o = make_float4(acc.x * inv, acc.y * inv, acc.z * inv, acc.w * inv);
    ((float4*)(out + (size_t)n * 128))[j] = o;
}

extern "C" void kernel_launch(void* const* d_in, const int* in_sizes, int n_in,
                              void* d_out, int out_size, void* d_ws, size_t ws_size,
                              hipStream_t stream) {
    const float* feat  = (const float*)d_in[0];
    const float* coord = (const float*)d_in[1];
    const int*   graph = (const int*)d_in[2];
    const float* qkv_w = (const float*)d_in[3];
    const float* qkv_b = (const float*)d_in[4];
    const float* rpe_w = (const float*)d_in[5];
    const float* rpe_b = (const float*)d_in[6];
    float* out = (float*)d_out;

    float* qkv        = (float*)d_ws;                  // NN x 384 fp32
    int*   deg        = (int*)(qkv + (size_t)NN * 384);
    int*   row_start  = deg + NN;
    int*   cursor     = row_start + NN;
    int*   counter    = cursor + NN;
    int*   sorted_src = counter + 1;

    hipMemsetAsync(deg, 0, NN * sizeof(int), stream);
    hipMemsetAsync(counter, 0, sizeof(int), stream);

    qkv_gemm<<<dim3(391, 3), 256, 0, stream>>>(feat, qkv_w, qkv_b, qkv);
    k_hist   <<<dim3((NE + 255) / 256), 256, 0, stream>>>(graph, deg);
    k_offsets<<<dim3((NN + 255) / 256), 256, 0, stream>>>(deg, row_start, cursor, counter);
    k_scatter<<<dim3((NE + 255) / 256), 256, 0, stream>>>(graph, cursor, sorted_src);
    node_attn<<<dim3((NN + 7) / 8), 256, 0, stream>>>(qkv, coord, row_start, deg,
                                                      sorted_src, rpe_w, rpe_b, out);
}

// Round 5
// 327.003 us; speedup vs baseline: 20.9722x; 1.1474x over previous
//
#include <hip/hip_runtime.h>
#include <hip/hip_bf16.h>

#define NN 50000
#define NE 800000

static __device__ __forceinline__ unsigned short f2bf(float x) {
    unsigned u = __float_as_uint(x);
    unsigned r = (u + 0x7fffu + ((u >> 16) & 1u)) >> 16;   // round-to-nearest-even
    return (unsigned short)r;
}
static __device__ __forceinline__ void bf4(const ushort4 u, float f[4]) {
    f[0] = __uint_as_float(((unsigned)u.x) << 16);
    f[1] = __uint_as_float(((unsigned)u.y) << 16);
    f[2] = __uint_as_float(((unsigned)u.z) << 16);
    f[3] = __uint_as_float(((unsigned)u.w) << 16);
}

// ---------------------------------------------------------------------------
// Kernel 1: fused QKV GEMM. 128x128 tile/block, 256 threads, 8x8 micro-tile.
// Epilogue: q block (blockIdx.y==0) -> fp32 qbuf[N][128];
//           k,v blocks (y==1,2)    -> bf16 kvbuf[N][256] (k: 0..127, v: 128..255).
// bf16 k/v halves the edge-phase gather bytes (the dominant traffic).
// ---------------------------------------------------------------------------
__global__ __launch_bounds__(256) void qkv_gemm(
    const float* __restrict__ feat, const float* __restrict__ w,
    const float* __restrict__ bias, float* __restrict__ qbuf,
    unsigned short* __restrict__ kvbuf)
{
    __shared__ float As[16][128];   // [k][row]
    __shared__ float Bs[16][128];   // [k][col]
    const int t  = threadIdx.x;
    const int tx = t & 15;
    const int ty = t >> 4;
    const int bm = blockIdx.x * 128;
    const int bc = blockIdx.y * 128;

    float acc[8][8];
#pragma unroll
    for (int i = 0; i < 8; ++i)
#pragma unroll
        for (int j = 0; j < 8; ++j) acc[i][j] = 0.f;

    const int outer = t & 127;
    const int kq0   = t >> 7;

    for (int k0 = 0; k0 < 128; k0 += 16) {
#pragma unroll
        for (int r = 0; r < 2; ++r) {
            int q = kq0 + r * 2;
            int ga = bm + outer;
            float4 a4 = (ga < NN)
                ? *(const float4*)(feat + (size_t)ga * 128 + k0 + q * 4)
                : make_float4(0.f, 0.f, 0.f, 0.f);
            As[q * 4 + 0][outer] = a4.x; As[q * 4 + 1][outer] = a4.y;
            As[q * 4 + 2][outer] = a4.z; As[q * 4 + 3][outer] = a4.w;
            int gb = bc + outer;
            float4 b4 = *(const float4*)(w + (size_t)gb * 128 + k0 + q * 4);
            Bs[q * 4 + 0][outer] = b4.x; Bs[q * 4 + 1][outer] = b4.y;
            Bs[q * 4 + 2][outer] = b4.z; Bs[q * 4 + 3][outer] = b4.w;
        }
        __syncthreads();
#pragma unroll
        for (int k = 0; k < 16; ++k) {
            float4 a0 = *(const float4*)&As[k][ty * 4];
            float4 a1 = *(const float4*)&As[k][64 + ty * 4];
            float4 b0 = *(const float4*)&Bs[k][tx * 4];
            float4 b1 = *(const float4*)&Bs[k][64 + tx * 4];
            float ar[8] = {a0.x, a0.y, a0.z, a0.w, a1.x, a1.y, a1.z, a1.w};
            float br[8] = {b0.x, b0.y, b0.z, b0.w, b1.x, b1.y, b1.z, b1.w};
#pragma unroll
            for (int i = 0; i < 8; ++i)
#pragma unroll
                for (int j = 0; j < 8; ++j)
                    acc[i][j] += ar[i] * br[j];
        }
        __syncthreads();
    }

    float bj[8];
#pragma unroll
    for (int j = 0; j < 8; ++j) {
        int col = bc + ((j < 4) ? (tx * 4 + j) : (64 + tx * 4 + (j - 4)));
        bj[j] = bias[col];
    }
    const int isQ = (blockIdx.y == 0);
#pragma unroll
    for (int i = 0; i < 8; ++i) {
        int row = bm + ((i < 4) ? (ty * 4 + i) : (64 + ty * 4 + (i - 4)));
        if (row >= NN) continue;
        float o[8];
#pragma unroll
        for (int j = 0; j < 8; ++j) o[j] = acc[i][j] + bj[j];
        if (isQ) {
            *(float4*)(qbuf + (size_t)row * 128 + tx * 4)      = make_float4(o[0], o[1], o[2], o[3]);
            *(float4*)(qbuf + (size_t)row * 128 + 64 + tx * 4) = make_float4(o[4], o[5], o[6], o[7]);
        } else {
            int off = bc - 128;   // 0 for k-block, 128 for v-block
            *(ushort4*)(kvbuf + (size_t)row * 256 + off + tx * 4) =
                make_ushort4(f2bf(o[0]), f2bf(o[1]), f2bf(o[2]), f2bf(o[3]));
            *(ushort4*)(kvbuf + (size_t)row * 256 + off + 64 + tx * 4) =
                make_ushort4(f2bf(o[4]), f2bf(o[5]), f2bf(o[6]), f2bf(o[7]));
        }
    }
}

// ---------------------------------------------------------------------------
// CSR build (unordered segments)
// ---------------------------------------------------------------------------
__global__ __launch_bounds__(256) void k_hist(
    const int* __restrict__ graph, int* __restrict__ deg)
{
    int e = blockIdx.x * 256 + threadIdx.x;
    if (e < NE) atomicAdd(&deg[graph[e]], 1);
}

__global__ __launch_bounds__(256) void k_offsets(
    const int* __restrict__ deg, int* __restrict__ row_start,
    int* __restrict__ cursor, int* __restrict__ counter)
{
    int n = blockIdx.x * 256 + threadIdx.x;
    int lane = threadIdx.x & 63;
    int d = (n < NN) ? deg[n] : 0;
    int x = d;
#pragma unroll
    for (int off = 1; off < 64; off <<= 1) {
        int y = __shfl_up(x, off);
        if (lane >= off) x += y;
    }
    int wave_base = 0;
    if (lane == 63) wave_base = atomicAdd(counter, x);
    wave_base = __shfl(wave_base, 63);
    if (n < NN) {
        int s = wave_base + x - d;
        row_start[n] = s;
        cursor[n] = s;
    }
}

__global__ __launch_bounds__(256) void k_scatter(
    const int* __restrict__ graph, int* __restrict__ cursor,
    int* __restrict__ sorted_src)
{
    int e = blockIdx.x * 256 + threadIdx.x;
    if (e < NE) {
        int dst = graph[e];
        int src = graph[NE + e];
        int slot = atomicAdd(&cursor[dst], 1);
        sorted_src[slot] = src;
    }
}

// ---------------------------------------------------------------------------
// Kernel 2: per-node attention, bf16 k/v gathers, fp32 math. 32 lanes/node.
// 2x unrolled edge loop for memory-level parallelism. Zero fp32 atomics.
// ---------------------------------------------------------------------------
__global__ __launch_bounds__(256) void node_attn(
    const float* __restrict__ qbuf, const unsigned short* __restrict__ kvbuf,
    const float* __restrict__ coord,
    const int* __restrict__ row_start, const int* __restrict__ deg,
    const int* __restrict__ sorted_src, const float* __restrict__ rpe_w,
    const float* __restrict__ rpe_b, float* __restrict__ out)
{
    __shared__ float s_rw[12];
    __shared__ float s_rb[4];
    const int t = threadIdx.x;
    if (t < 12) {
        int h = t / 3, p = t % 3;
        float s = 0.f;
        for (int d = 0; d < 32; ++d) s += rpe_w[(h * 32 + d) * 3 + p];
        s_rw[t] = s;
    } else if (t < 16) {
        int h = t - 12;
        float s = 0.f;
        for (int d = 0; d < 32; ++d) s += rpe_b[h * 32 + d];
        s_rb[h] = s;
    }
    __syncthreads();

    const int n = blockIdx.x * 8 + (t >> 5);
    if (n >= NN) return;
    const int j = t & 31;
    const int h = j >> 3;

    const float4 q4 = ((const float4*)(qbuf + (size_t)n * 128))[j];
    const float c0 = coord[n * 3 + 0];
    const float c1 = coord[n * 3 + 1];
    const float c2 = coord[n * 3 + 2];
    const float rw0 = s_rw[h * 3 + 0], rw1 = s_rw[h * 3 + 1],
                rw2 = s_rw[h * 3 + 2], rb = s_rb[h];

    const int start = row_start[n];
    const int d = deg[n];

    float4 acc = make_float4(0.f, 0.f, 0.f, 0.f);
    float den = 0.f;

    const ushort4* kvb = (const ushort4*)kvbuf;   // 64 x ushort4 per row

    int i = 0;
    for (; i + 1 < d; i += 2) {
        int s0 = sorted_src[start + i];
        int s1 = sorted_src[start + i + 1];
        const ushort4* r0 = kvb + (size_t)s0 * 64;
        const ushort4* r1 = kvb + (size_t)s1 * 64;
        ushort4 k0u = r0[j],  v0u = r0[32 + j];
        ushort4 k1u = r1[j],  v1u = r1[32 + j];
        float x00 = coord[s0 * 3 + 0], x01 = coord[s0 * 3 + 1], x02 = coord[s0 * 3 + 2];
        float x10 = coord[s1 * 3 + 0], x11 = coord[s1 * 3 + 1], x12 = coord[s1 * 3 + 2];

        float k0[4], v0[4], k1[4], v1[4];
        bf4(k0u, k0); bf4(v0u, v0); bf4(k1u, k1); bf4(v1u, v1);

        float p0 = q4.x * k0[0] + q4.y * k0[1] + q4.z * k0[2] + q4.w * k0[3];
        float p1 = q4.x * k1[0] + q4.y * k1[1] + q4.z * k1[2] + q4.w * k1[3];
        p0 += __shfl_xor(p0, 1); p1 += __shfl_xor(p1, 1);
        p0 += __shfl_xor(p0, 2); p1 += __shfl_xor(p1, 2);
        p0 += __shfl_xor(p0, 4); p1 += __shfl_xor(p1, 4);

        float e0 = expf(p0 + (c0 - x00) * rw0 + (c1 - x01) * rw1 + (c2 - x02) * rw2 + rb);
        float e1 = expf(p1 + (c0 - x10) * rw0 + (c1 - x11) * rw1 + (c2 - x12) * rw2 + rb);
        den += e0 + e1;
        acc.x += e0 * v0[0] + e1 * v1[0];
        acc.y += e0 * v0[1] + e1 * v1[1];
        acc.z += e0 * v0[2] + e1 * v1[2];
        acc.w += e0 * v0[3] + e1 * v1[3];
    }
    if (i < d) {
        int s0 = sorted_src[start + i];
        const ushort4* r0 = kvb + (size_t)s0 * 64;
        ushort4 k0u = r0[j], v0u = r0[32 + j];
        float x00 = coord[s0 * 3 + 0], x01 = coord[s0 * 3 + 1], x02 = coord[s0 * 3 + 2];
        float k0[4], v0[4];
        bf4(k0u, k0); bf4(v0u, v0);
        float p0 = q4.x * k0[0] + q4.y * k0[1] + q4.z * k0[2] + q4.w * k0[3];
        p0 += __shfl_xor(p0, 1);
        p0 += __shfl_xor(p0, 2);
        p0 += __shfl_xor(p0, 4);
        float e0 = expf(p0 + (c0 - x00) * rw0 + (c1 - x01) * rw1 + (c2 - x02) * rw2 + rb);
        den += e0;
        acc.x += e0 * v0[0]; acc.y += e0 * v0[1];
        acc.z += e0 * v0[2]; acc.w += e0 * v0[3];
    }

    float inv = (den > 0.f) ? 1.0f / den : 0.f;
    float4 o = make_float4(acc.x * inv, acc.y * inv, acc.z * inv, acc.w * inv);
    ((float4*)(out + (size_t)n * 128))[j] = o;
}

extern "C" void kernel_launch(void* const* d_in, const int* in_sizes, int n_in,
                              void* d_out, int out_size, void* d_ws, size_t ws_size,
                              hipStream_t stream) {
    const float* feat  = (const float*)d_in[0];
    const float* coord = (const float*)d_in[1];
    const int*   graph = (const int*)d_in[2];
    const float* qkv_w = (const float*)d_in[3];
    const float* qkv_b = (const float*)d_in[4];
    const float* rpe_w = (const float*)d_in[5];
    const float* rpe_b = (const float*)d_in[6];
    float* out = (float*)d_out;

    float*          qbuf  = (float*)d_ws;                         // NN x 128 fp32
    unsigned short* kvbuf = (unsigned short*)(qbuf + (size_t)NN * 128);  // NN x 256 bf16
    int* deg        = (int*)(kvbuf + (size_t)NN * 256);
    int* row_start  = deg + NN;
    int* cursor     = row_start + NN;
    int* counter    = cursor + NN;
    int* sorted_src = counter + 1;

    hipMemsetAsync(deg, 0, NN * sizeof(int), stream);
    hipMemsetAsync(counter, 0, sizeof(int), stream);

    qkv_gemm<<<dim3(391, 3), 256, 0, stream>>>(feat, qkv_w, qkv_b, qbuf, kvbuf);
    k_hist   <<<dim3((NE + 255) / 256), 256, 0, stream>>>(graph, deg);
    k_offsets<<<dim3((NN + 255) / 256), 256, 0, stream>>>(deg, row_start, cursor, counter);
    k_scatter<<<dim3((NE + 255) / 256), 256, 0, stream>>>(graph, cursor, sorted_src);
    node_attn<<<dim3((NN + 7) / 8), 256, 0, stream>>>(qbuf, kvbuf, coord, row_start, deg,
                                                      sorted_src, rpe_w, rpe_b, out);
}

// Round 6
// 288.595 us; speedup vs baseline: 23.7633x; 1.1331x over previous
//
#include <hip/hip_runtime.h>
#include <hip/hip_bf16.h>

#define NN 50000
#define NE 800000

static __device__ __forceinline__ unsigned short f2bf(float x) {
    unsigned u = __float_as_uint(x);
    unsigned r = (u + 0x7fffu + ((u >> 16) & 1u)) >> 16;   // round-to-nearest-even
    return (unsigned short)r;
}
static __device__ __forceinline__ void bf4(const ushort4 u, float f[4]) {
    f[0] = __uint_as_float(((unsigned)u.x) << 16);
    f[1] = __uint_as_float(((unsigned)u.y) << 16);
    f[2] = __uint_as_float(((unsigned)u.z) << 16);
    f[3] = __uint_as_float(((unsigned)u.w) << 16);
}

// ---------------------------------------------------------------------------
// Kernel 1: fused QKV GEMM + edge histogram.
// GEMM blocks (y=0..2): 128x128 tile, 256 threads, 8x8 micro-tile, register-
// prefetch pipeline (global->regs for slab s+1 issued before compute of slab s,
// single 16KB LDS buffer). Epilogue: y==0 -> fp32 qbuf; y==1,2 -> bf16 kvbuf.
// Hist blocks (y==3): grid-stride degree histogram (independent of GEMM;
// folded here so it overlaps instead of serializing on the stream).
// ---------------------------------------------------------------------------
__global__ __launch_bounds__(256) void qkv_gemm(
    const float* __restrict__ feat, const float* __restrict__ w,
    const float* __restrict__ bias, float* __restrict__ qbuf,
    unsigned short* __restrict__ kvbuf,
    const int* __restrict__ graph, int* __restrict__ deg)
{
    if (blockIdx.y == 3) {          // histogram path (uniform branch per block)
        int stride = gridDim.x * 256;
        for (int e = blockIdx.x * 256 + threadIdx.x; e < NE; e += stride)
            atomicAdd(&deg[graph[e]], 1);
        return;
    }

    __shared__ float As[16][128];   // [k][row]
    __shared__ float Bs[16][128];   // [k][col]
    const int t  = threadIdx.x;
    const int tx = t & 15;
    const int ty = t >> 4;
    const int bm = blockIdx.x * 128;
    const int bc = blockIdx.y * 128;

    float acc[8][8];
#pragma unroll
    for (int i = 0; i < 8; ++i)
#pragma unroll
        for (int j = 0; j < 8; ++j) acc[i][j] = 0.f;

    const int outer = t & 127;
    const int kq0   = t >> 7;       // 0..1 -> stages float4 chunks kq0, kq0+2

    float4 pa[2], pb[2];
    {   // prefetch slab 0
        int ga = bm + outer, gb = bc + outer;
#pragma unroll
        for (int r = 0; r < 2; ++r) {
            int q = kq0 + r * 2;
            pa[r] = (ga < NN) ? *(const float4*)(feat + (size_t)ga * 128 + q * 4)
                              : make_float4(0.f, 0.f, 0.f, 0.f);
            pb[r] = *(const float4*)(w + (size_t)gb * 128 + q * 4);
        }
    }

    for (int s = 0; s < 8; ++s) {
        if (s) __syncthreads();     // previous slab's compute reads done
#pragma unroll
        for (int r = 0; r < 2; ++r) {
            int q = kq0 + r * 2;
            As[q * 4 + 0][outer] = pa[r].x; As[q * 4 + 1][outer] = pa[r].y;
            As[q * 4 + 2][outer] = pa[r].z; As[q * 4 + 3][outer] = pa[r].w;
            Bs[q * 4 + 0][outer] = pb[r].x; Bs[q * 4 + 1][outer] = pb[r].y;
            Bs[q * 4 + 2][outer] = pb[r].z; Bs[q * 4 + 3][outer] = pb[r].w;
        }
        __syncthreads();
        if (s < 7) {                // prefetch next slab; completes during compute
            int k0 = (s + 1) * 16;
            int ga = bm + outer, gb = bc + outer;
#pragma unroll
            for (int r = 0; r < 2; ++r) {
                int q = kq0 + r * 2;
                pa[r] = (ga < NN) ? *(const float4*)(feat + (size_t)ga * 128 + k0 + q * 4)
                                  : make_float4(0.f, 0.f, 0.f, 0.f);
                pb[r] = *(const float4*)(w + (size_t)gb * 128 + k0 + q * 4);
            }
        }
#pragma unroll
        for (int k = 0; k < 16; ++k) {
            float4 a0 = *(const float4*)&As[k][ty * 4];
            float4 a1 = *(const float4*)&As[k][64 + ty * 4];
            float4 b0 = *(const float4*)&Bs[k][tx * 4];
            float4 b1 = *(const float4*)&Bs[k][64 + tx * 4];
            float ar[8] = {a0.x, a0.y, a0.z, a0.w, a1.x, a1.y, a1.z, a1.w};
            float br[8] = {b0.x, b0.y, b0.z, b0.w, b1.x, b1.y, b1.z, b1.w};
#pragma unroll
            for (int i = 0; i < 8; ++i)
#pragma unroll
                for (int j = 0; j < 8; ++j)
                    acc[i][j] += ar[i] * br[j];
        }
    }

    float bj[8];
#pragma unroll
    for (int j = 0; j < 8; ++j) {
        int col = bc + ((j < 4) ? (tx * 4 + j) : (64 + tx * 4 + (j - 4)));
        bj[j] = bias[col];
    }
    const int isQ = (blockIdx.y == 0);
#pragma unroll
    for (int i = 0; i < 8; ++i) {
        int row = bm + ((i < 4) ? (ty * 4 + i) : (64 + ty * 4 + (i - 4)));
        if (row >= NN) continue;
        float o[8];
#pragma unroll
        for (int j = 0; j < 8; ++j) o[j] = acc[i][j] + bj[j];
        if (isQ) {
            *(float4*)(qbuf + (size_t)row * 128 + tx * 4)      = make_float4(o[0], o[1], o[2], o[3]);
            *(float4*)(qbuf + (size_t)row * 128 + 64 + tx * 4) = make_float4(o[4], o[5], o[6], o[7]);
        } else {
            int off = bc - 128;   // 0 for k-block, 128 for v-block
            *(ushort4*)(kvbuf + (size_t)row * 256 + off + tx * 4) =
                make_ushort4(f2bf(o[0]), f2bf(o[1]), f2bf(o[2]), f2bf(o[3]));
            *(ushort4*)(kvbuf + (size_t)row * 256 + off + 64 + tx * 4) =
                make_ushort4(f2bf(o[4]), f2bf(o[5]), f2bf(o[6]), f2bf(o[7]));
        }
    }
}

// ---------------------------------------------------------------------------
// CSR build (unordered segments)
// ---------------------------------------------------------------------------
__global__ __launch_bounds__(256) void k_offsets(
    const int* __restrict__ deg, int* __restrict__ row_start,
    int* __restrict__ cursor, int* __restrict__ counter)
{
    int n = blockIdx.x * 256 + threadIdx.x;
    int lane = threadIdx.x & 63;
    int d = (n < NN) ? deg[n] : 0;
    int x = d;
#pragma unroll
    for (int off = 1; off < 64; off <<= 1) {
        int y = __shfl_up(x, off);
        if (lane >= off) x += y;
    }
    int wave_base = 0;
    if (lane == 63) wave_base = atomicAdd(counter, x);
    wave_base = __shfl(wave_base, 63);
    if (n < NN) {
        int s = wave_base + x - d;
        row_start[n] = s;
        cursor[n] = s;
    }
}

__global__ __launch_bounds__(256) void k_scatter(
    const int* __restrict__ graph, int* __restrict__ cursor,
    int* __restrict__ sorted_src)
{
    int e = blockIdx.x * 256 + threadIdx.x;
    if (e < NE) {
        int dst = graph[e];
        int src = graph[NE + e];
        int slot = atomicAdd(&cursor[dst], 1);
        sorted_src[slot] = src;
    }
}

// ---------------------------------------------------------------------------
// Kernel 2: per-node attention, bf16 k/v gathers, fp32 math. 32 lanes/node.
// 2x unrolled edge loop for memory-level parallelism. Zero fp32 atomics.
// ---------------------------------------------------------------------------
__global__ __launch_bounds__(256) void node_attn(
    const float* __restrict__ qbuf, const unsigned short* __restrict__ kvbuf,
    const float* __restrict__ coord,
    const int* __restrict__ row_start, const int* __restrict__ deg,
    const int* __restrict__ sorted_src, const float* __restrict__ rpe_w,
    const float* __restrict__ rpe_b, float* __restrict__ out)
{
    __shared__ float s_rw[12];
    __shared__ float s_rb[4];
    const int t = threadIdx.x;
    if (t < 12) {
        int h = t / 3, p = t % 3;
        float s = 0.f;
        for (int d = 0; d < 32; ++d) s += rpe_w[(h * 32 + d) * 3 + p];
        s_rw[t] = s;
    } else if (t < 16) {
        int h = t - 12;
        float s = 0.f;
        for (int d = 0; d < 32; ++d) s += rpe_b[h * 32 + d];
        s_rb[h] = s;
    }
    __syncthreads();

    const int n = blockIdx.x * 8 + (t >> 5);
    if (n >= NN) return;
    const int j = t & 31;
    const int h = j >> 3;

    const float4 q4 = ((const float4*)(qbuf + (size_t)n * 128))[j];
    const float c0 = coord[n * 3 + 0];
    const float c1 = coord[n * 3 + 1];
    const float c2 = coord[n * 3 + 2];
    const float rw0 = s_rw[h * 3 + 0], rw1 = s_rw[h * 3 + 1],
                rw2 = s_rw[h * 3 + 2], rb = s_rb[h];

    const int start = row_start[n];
    const int d = deg[n];

    float4 acc = make_float4(0.f, 0.f, 0.f, 0.f);
    float den = 0.f;

    const ushort4* kvb = (const ushort4*)kvbuf;   // 64 x ushort4 per row

    int i = 0;
    for (; i + 1 < d; i += 2) {
        int s0 = sorted_src[start + i];
        int s1 = sorted_src[start + i + 1];
        const ushort4* r0 = kvb + (size_t)s0 * 64;
        const ushort4* r1 = kvb + (size_t)s1 * 64;
        ushort4 k0u = r0[j],  v0u = r0[32 + j];
        ushort4 k1u = r1[j],  v1u = r1[32 + j];
        float x00 = coord[s0 * 3 + 0], x01 = coord[s0 * 3 + 1], x02 = coord[s0 * 3 + 2];
        float x10 = coord[s1 * 3 + 0], x11 = coord[s1 * 3 + 1], x12 = coord[s1 * 3 + 2];

        float k0[4], v0[4], k1[4], v1[4];
        bf4(k0u, k0); bf4(v0u, v0); bf4(k1u, k1); bf4(v1u, v1);

        float p0 = q4.x * k0[0] + q4.y * k0[1] + q4.z * k0[2] + q4.w * k0[3];
        float p1 = q4.x * k1[0] + q4.y * k1[1] + q4.z * k1[2] + q4.w * k1[3];
        p0 += __shfl_xor(p0, 1); p1 += __shfl_xor(p1, 1);
        p0 += __shfl_xor(p0, 2); p1 += __shfl_xor(p1, 2);
        p0 += __shfl_xor(p0, 4); p1 += __shfl_xor(p1, 4);

        float e0 = expf(p0 + (c0 - x00) * rw0 + (c1 - x01) * rw1 + (c2 - x02) * rw2 + rb);
        float e1 = expf(p1 + (c0 - x10) * rw0 + (c1 - x11) * rw1 + (c2 - x12) * rw2 + rb);
        den += e0 + e1;
        acc.x += e0 * v0[0] + e1 * v1[0];
        acc.y += e0 * v0[1] + e1 * v1[1];
        acc.z += e0 * v0[2] + e1 * v1[2];
        acc.w += e0 * v0[3] + e1 * v1[3];
    }
    if (i < d) {
        int s0 = sorted_src[start + i];
        const ushort4* r0 = kvb + (size_t)s0 * 64;
        ushort4 k0u = r0[j], v0u = r0[32 + j];
        float x00 = coord[s0 * 3 + 0], x01 = coord[s0 * 3 + 1], x02 = coord[s0 * 3 + 2];
        float k0[4], v0[4];
        bf4(k0u, k0); bf4(v0u, v0);
        float p0 = q4.x * k0[0] + q4.y * k0[1] + q4.z * k0[2] + q4.w * k0[3];
        p0 += __shfl_xor(p0, 1);
        p0 += __shfl_xor(p0, 2);
        p0 += __shfl_xor(p0, 4);
        float e0 = expf(p0 + (c0 - x00) * rw0 + (c1 - x01) * rw1 + (c2 - x02) * rw2 + rb);
        den += e0;
        acc.x += e0 * v0[0]; acc.y += e0 * v0[1];
        acc.z += e0 * v0[2]; acc.w += e0 * v0[3];
    }

    float inv = (den > 0.f) ? 1.0f / den : 0.f;
    float4 o = make_float4(acc.x * inv, acc.y * inv, acc.z * inv, acc.w * inv);
    ((float4*)(out + (size_t)n * 128))[j] = o;
}

extern "C" void kernel_launch(void* const* d_in, const int* in_sizes, int n_in,
                              void* d_out, int out_size, void* d_ws, size_t ws_size,
                              hipStream_t stream) {
    const float* feat  = (const float*)d_in[0];
    const float* coord = (const float*)d_in[1];
    const int*   graph = (const int*)d_in[2];
    const float* qkv_w = (const float*)d_in[3];
    const float* qkv_b = (const float*)d_in[4];
    const float* rpe_w = (const float*)d_in[5];
    const float* rpe_b = (const float*)d_in[6];
    float* out = (float*)d_out;

    float*          qbuf  = (float*)d_ws;                         // NN x 128 fp32
    unsigned short* kvbuf = (unsigned short*)(qbuf + (size_t)NN * 128);  // NN x 256 bf16
    int* deg        = (int*)(kvbuf + (size_t)NN * 256);
    int* row_start  = deg + NN;
    int* cursor     = row_start + NN;
    int* counter    = cursor + NN;
    int* sorted_src = counter + 1;

    hipMemsetAsync(deg, 0, NN * sizeof(int), stream);
    hipMemsetAsync(counter, 0, sizeof(int), stream);

    qkv_gemm <<<dim3(391, 4), 256, 0, stream>>>(feat, qkv_w, qkv_b, qbuf, kvbuf,
                                                graph, deg);
    k_offsets<<<dim3((NN + 255) / 256), 256, 0, stream>>>(deg, row_start, cursor, counter);
    k_scatter<<<dim3((NE + 255) / 256), 256, 0, stream>>>(graph, cursor, sorted_src);
    node_attn<<<dim3((NN + 7) / 8), 256, 0, stream>>>(qbuf, kvbuf, coord, row_start, deg,
                                                      sorted_src, rpe_w, rpe_b, out);
}

// Round 7
// 274.207 us; speedup vs baseline: 25.0102x; 1.0525x over previous
//
#include <hip/hip_runtime.h>
#include <hip/hip_bf16.h>

#define NN 50000
#define NE 800000

typedef __attribute__((ext_vector_type(8))) short short8;   // 8 bf16 = 4 VGPRs
typedef __attribute__((ext_vector_type(4))) float f32x4;

static __device__ __forceinline__ unsigned short f2bf(float x) {
    unsigned u = __float_as_uint(x);
    unsigned r = (u + 0x7fffu + ((u >> 16) & 1u)) >> 16;   // RNE
    return (unsigned short)r;
}
static __device__ __forceinline__ float bf2f(unsigned short s) {
    return __uint_as_float(((unsigned)s) << 16);
}
static __device__ __forceinline__ void bf4(const ushort4 u, float f[4]) {
    f[0] = __uint_as_float(((unsigned)u.x) << 16);
    f[1] = __uint_as_float(((unsigned)u.y) << 16);
    f[2] = __uint_as_float(((unsigned)u.z) << 16);
    f[3] = __uint_as_float(((unsigned)u.w) << 16);
}

// ---------------------------------------------------------------------------
// Kernel 1: fused QKV GEMM (bf16x3 split-precision MFMA) + edge histogram.
// GEMM blocks (y=0..2): 128x128 tile, 4 waves (2x2), each wave 4x4 tiles of
// 16x16x32 MFMA. fp32 operands split hi/lo bf16; acc = hi*hi + hi*lo + lo*hi
// in fp32 (error ~2^-17 rel — negligible vs bf16 k/v storage rounding).
// A (feat) and B (qkv_w) both [row][k] row-major — w is already B^T form.
// LDS rows padded to 40 shorts: frag ds_read_b128 at 2-way conflict (free).
// Epilogue: y==0 -> fp32 qbuf; y==1,2 -> bf16 kvbuf.
// Hist blocks (y==3): grid-stride degree histogram (overlaps GEMM).
// ---------------------------------------------------------------------------
__global__ __launch_bounds__(256) void qkv_gemm(
    const float* __restrict__ feat, const float* __restrict__ w,
    const float* __restrict__ bias, float* __restrict__ qbuf,
    unsigned short* __restrict__ kvbuf,
    const int* __restrict__ graph, int* __restrict__ deg)
{
    if (blockIdx.y == 3) {          // histogram path (uniform per block)
        int stride = gridDim.x * 256;
        for (int e = blockIdx.x * 256 + threadIdx.x; e < NE; e += stride)
            atomicAdd(&deg[graph[e]], 1);
        return;
    }

    __shared__ __align__(16) short Ah[128][40];   // 10 KB each, 40 KB total
    __shared__ __align__(16) short Al[128][40];
    __shared__ __align__(16) short Bh[128][40];
    __shared__ __align__(16) short Bl[128][40];

    const int t  = threadIdx.x;
    const int bm = blockIdx.x * 128;
    const int bc = blockIdx.y * 128;    // 0 / 128 / 256 within 384 cols

    const int wave = t >> 6;
    const int lane = t & 63;
    const int wr = wave & 1;            // wave row (64 rows each)
    const int wc = wave >> 1;           // wave col (64 cols each)
    const int qd = lane >> 4;           // quad 0..3
    const int l15 = lane & 15;

    f32x4 acc[4][4];
#pragma unroll
    for (int i = 0; i < 4; ++i)
#pragma unroll
        for (int j = 0; j < 4; ++j)
            acc[i][j] = (f32x4){0.f, 0.f, 0.f, 0.f};

    for (int ks = 0; ks < 4; ++ks) {
        const int k0 = ks * 32;
        if (ks) __syncthreads();        // prev compute done before overwrite
        // ---- stage 128x32 slabs of A and B as hi/lo bf16 ----
#pragma unroll
        for (int i = 0; i < 4; ++i) {
            int idx = i * 256 + t;          // 0..1023
            int r  = idx >> 3;
            int c4 = (idx & 7) * 4;
            int ga = bm + r;
            float4 a4 = (ga < NN)
                ? *(const float4*)(feat + (size_t)ga * 128 + k0 + c4)
                : make_float4(0.f, 0.f, 0.f, 0.f);
            float4 b4 = *(const float4*)(w + (size_t)(bc + r) * 128 + k0 + c4);
            unsigned short h;
            short4 hv, lv;
            h = f2bf(a4.x); hv.x = (short)h; lv.x = (short)f2bf(a4.x - bf2f(h));
            h = f2bf(a4.y); hv.y = (short)h; lv.y = (short)f2bf(a4.y - bf2f(h));
            h = f2bf(a4.z); hv.z = (short)h; lv.z = (short)f2bf(a4.z - bf2f(h));
            h = f2bf(a4.w); hv.w = (short)h; lv.w = (short)f2bf(a4.w - bf2f(h));
            *(short4*)&Ah[r][c4] = hv;
            *(short4*)&Al[r][c4] = lv;
            h = f2bf(b4.x); hv.x = (short)h; lv.x = (short)f2bf(b4.x - bf2f(h));
            h = f2bf(b4.y); hv.y = (short)h; lv.y = (short)f2bf(b4.y - bf2f(h));
            h = f2bf(b4.z); hv.z = (short)h; lv.z = (short)f2bf(b4.z - bf2f(h));
            h = f2bf(b4.w); hv.w = (short)h; lv.w = (short)f2bf(b4.w - bf2f(h));
            *(short4*)&Bh[r][c4] = hv;
            *(short4*)&Bl[r][c4] = lv;
        }
        __syncthreads();
        // ---- fragments + MFMA ----
        short8 ah[4], al[4];
#pragma unroll
        for (int i = 0; i < 4; ++i) {
            ah[i] = *(const short8*)&Ah[wr * 64 + 16 * i + l15][qd * 8];
            al[i] = *(const short8*)&Al[wr * 64 + 16 * i + l15][qd * 8];
        }
#pragma unroll
        for (int j = 0; j < 4; ++j) {
            short8 bh = *(const short8*)&Bh[wc * 64 + 16 * j + l15][qd * 8];
            short8 bl = *(const short8*)&Bl[wc * 64 + 16 * j + l15][qd * 8];
#pragma unroll
            for (int i = 0; i < 4; ++i) {
                acc[i][j] = __builtin_amdgcn_mfma_f32_16x16x32_bf16(al[i], bh, acc[i][j], 0, 0, 0);
                acc[i][j] = __builtin_amdgcn_mfma_f32_16x16x32_bf16(ah[i], bl, acc[i][j], 0, 0, 0);
                acc[i][j] = __builtin_amdgcn_mfma_f32_16x16x32_bf16(ah[i], bh, acc[i][j], 0, 0, 0);
            }
        }
    }

    // ---- epilogue: C/D layout col=lane&15, row=quad*4+reg ----
    float bj[4];
#pragma unroll
    for (int j = 0; j < 4; ++j)
        bj[j] = bias[bc + wc * 64 + 16 * j + l15];

    const int isQ = (blockIdx.y == 0);
#pragma unroll
    for (int i = 0; i < 4; ++i) {
#pragma unroll
        for (int rg = 0; rg < 4; ++rg) {
            int row = bm + wr * 64 + 16 * i + qd * 4 + rg;
            if (row >= NN) continue;
#pragma unroll
            for (int j = 0; j < 4; ++j) {
                float v = acc[i][j][rg] + bj[j];
                int col = wc * 64 + 16 * j + l15;
                if (isQ) qbuf[(size_t)row * 128 + col] = v;
                else     kvbuf[(size_t)row * 256 + (bc - 128) + col] = f2bf(v);
            }
        }
    }
}

// ---------------------------------------------------------------------------
// CSR build (unordered segments)
// ---------------------------------------------------------------------------
__global__ __launch_bounds__(256) void k_offsets(
    const int* __restrict__ deg, int* __restrict__ row_start,
    int* __restrict__ cursor, int* __restrict__ counter)
{
    int n = blockIdx.x * 256 + threadIdx.x;
    int lane = threadIdx.x & 63;
    int d = (n < NN) ? deg[n] : 0;
    int x = d;
#pragma unroll
    for (int off = 1; off < 64; off <<= 1) {
        int y = __shfl_up(x, off);
        if (lane >= off) x += y;
    }
    int wave_base = 0;
    if (lane == 63) wave_base = atomicAdd(counter, x);
    wave_base = __shfl(wave_base, 63);
    if (n < NN) {
        int s = wave_base + x - d;
        row_start[n] = s;
        cursor[n] = s;
    }
}

__global__ __launch_bounds__(256) void k_scatter(
    const int* __restrict__ graph, int* __restrict__ cursor,
    int* __restrict__ sorted_src)
{
    int e = blockIdx.x * 256 + threadIdx.x;
    if (e < NE) {
        int dst = graph[e];
        int src = graph[NE + e];
        int slot = atomicAdd(&cursor[dst], 1);
        sorted_src[slot] = src;
    }
}

// ---------------------------------------------------------------------------
// Kernel 2: per-node attention, bf16 k/v gathers, fp32 math. 32 lanes/node.
// ---------------------------------------------------------------------------
__global__ __launch_bounds__(256) void node_attn(
    const float* __restrict__ qbuf, const unsigned short* __restrict__ kvbuf,
    const float* __restrict__ coord,
    const int* __restrict__ row_start, const int* __restrict__ deg,
    const int* __restrict__ sorted_src, const float* __restrict__ rpe_w,
    const float* __restrict__ rpe_b, float* __restrict__ out)
{
    __shared__ float s_rw[12];
    __shared__ float s_rb[4];
    const int t = threadIdx.x;
    if (t < 12) {
        int h = t / 3, p = t % 3;
        float s = 0.f;
        for (int d = 0; d < 32; ++d) s += rpe_w[(h * 32 + d) * 3 + p];
        s_rw[t] = s;
    } else if (t < 16) {
        int h = t - 12;
        float s = 0.f;
        for (int d = 0; d < 32; ++d) s += rpe_b[h * 32 + d];
        s_rb[h] = s;
    }
    __syncthreads();

    const int n = blockIdx.x * 8 + (t >> 5);
    if (n >= NN) return;
    const int j = t & 31;
    const int h = j >> 3;

    const float4 q4 = ((const float4*)(qbuf + (size_t)n * 128))[j];
    const float c0 = coord[n * 3 + 0];
    const float c1 = coord[n * 3 + 1];
    const float c2 = coord[n * 3 + 2];
    const float rw0 = s_rw[h * 3 + 0], rw1 = s_rw[h * 3 + 1],
                rw2 = s_rw[h * 3 + 2], rb = s_rb[h];

    const int start = row_start[n];
    const int d = deg[n];

    float4 acc = make_float4(0.f, 0.f, 0.f, 0.f);
    float den = 0.f;

    const ushort4* kvb = (const ushort4*)kvbuf;   // 64 x ushort4 per row

    int i = 0;
    for (; i + 1 < d; i += 2) {
        int s0 = sorted_src[start + i];
        int s1 = sorted_src[start + i + 1];
        const ushort4* r0 = kvb + (size_t)s0 * 64;
        const ushort4* r1 = kvb + (size_t)s1 * 64;
        ushort4 k0u = r0[j],  v0u = r0[32 + j];
        ushort4 k1u = r1[j],  v1u = r1[32 + j];
        float x00 = coord[s0 * 3 + 0], x01 = coord[s0 * 3 + 1], x02 = coord[s0 * 3 + 2];
        float x10 = coord[s1 * 3 + 0], x11 = coord[s1 * 3 + 1], x12 = coord[s1 * 3 + 2];

        float k0[4], v0[4], k1[4], v1[4];
        bf4(k0u, k0); bf4(v0u, v0); bf4(k1u, k1); bf4(v1u, v1);

        float p0 = q4.x * k0[0] + q4.y * k0[1] + q4.z * k0[2] + q4.w * k0[3];
        float p1 = q4.x * k1[0] + q4.y * k1[1] + q4.z * k1[2] + q4.w * k1[3];
        p0 += __shfl_xor(p0, 1); p1 += __shfl_xor(p1, 1);
        p0 += __shfl_xor(p0, 2); p1 += __shfl_xor(p1, 2);
        p0 += __shfl_xor(p0, 4); p1 += __shfl_xor(p1, 4);

        float e0 = expf(p0 + (c0 - x00) * rw0 + (c1 - x01) * rw1 + (c2 - x02) * rw2 + rb);
        float e1 = expf(p1 + (c0 - x10) * rw0 + (c1 - x11) * rw1 + (c2 - x12) * rw2 + rb);
        den += e0 + e1;
        acc.x += e0 * v0[0] + e1 * v1[0];
        acc.y += e0 * v0[1] + e1 * v1[1];
        acc.z += e0 * v0[2] + e1 * v1[2];
        acc.w += e0 * v0[3] + e1 * v1[3];
    }
    if (i < d) {
        int s0 = sorted_src[start + i];
        const ushort4* r0 = kvb + (size_t)s0 * 64;
        ushort4 k0u = r0[j], v0u = r0[32 + j];
        float x00 = coord[s0 * 3 + 0], x01 = coord[s0 * 3 + 1], x02 = coord[s0 * 3 + 2];
        float k0[4], v0[4];
        bf4(k0u, k0); bf4(v0u, v0);
        float p0 = q4.x * k0[0] + q4.y * k0[1] + q4.z * k0[2] + q4.w * k0[3];
        p0 += __shfl_xor(p0, 1);
        p0 += __shfl_xor(p0, 2);
        p0 += __shfl_xor(p0, 4);
        float e0 = expf(p0 + (c0 - x00) * rw0 + (c1 - x01) * rw1 + (c2 - x02) * rw2 + rb);
        den += e0;
        acc.x += e0 * v0[0]; acc.y += e0 * v0[1];
        acc.z += e0 * v0[2]; acc.w += e0 * v0[3];
    }

    float inv = (den > 0.f) ? 1.0f / den : 0.f;
    float4 o = make_float4(acc.x * inv, acc.y * inv, acc.z * inv, acc.w * inv);
    ((float4*)(out + (size_t)n * 128))[j] = o;
}

extern "C" void kernel_launch(void* const* d_in, const int* in_sizes, int n_in,
                              void* d_out, int out_size, void* d_ws, size_t ws_size,
                              hipStream_t stream) {
    const float* feat  = (const float*)d_in[0];
    const float* coord = (const float*)d_in[1];
    const int*   graph = (const int*)d_in[2];
    const float* qkv_w = (const float*)d_in[3];
    const float* qkv_b = (const float*)d_in[4];
    const float* rpe_w = (const float*)d_in[5];
    const float* rpe_b = (const float*)d_in[6];
    float* out = (float*)d_out;

    float*          qbuf  = (float*)d_ws;                         // NN x 128 fp32
    unsigned short* kvbuf = (unsigned short*)(qbuf + (size_t)NN * 128);  // NN x 256 bf16
    int* deg        = (int*)(kvbuf + (size_t)NN * 256);
    int* row_start  = deg + NN;
    int* cursor     = row_start + NN;
    int* counter    = cursor + NN;
    int* sorted_src = counter + 1;

    hipMemsetAsync(deg, 0, NN * sizeof(int), stream);
    hipMemsetAsync(counter, 0, sizeof(int), stream);

    qkv_gemm <<<dim3(391, 4), 256, 0, stream>>>(feat, qkv_w, qkv_b, qbuf, kvbuf,
                                                graph, deg);
    k_offsets<<<dim3((NN + 255) / 256), 256, 0, stream>>>(deg, row_start, cursor, counter);
    k_scatter<<<dim3((NE + 255) / 256), 256, 0, stream>>>(graph, cursor, sorted_src);
    node_attn<<<dim3((NN + 7) / 8), 256, 0, stream>>>(qbuf, kvbuf, coord, row_start, deg,
                                                      sorted_src, rpe_w, rpe_b, out);
}